// Round 1
// 105.299 us; speedup vs baseline: 1.0309x; 1.0309x over previous
//
#include <hip/hip_runtime.h>
#include <hip/hip_bf16.h>
#include <math.h>

// B=2, C=128, T=5 (Tc=4 ctx), H=W=48, heads=64, PATCH=7 (pad 3), K=196.
#define BATCH 2
#define CCH 128
#define TT 5
#define TC 4
#define HH 48
#define WW 48
#define HWPIX 2304
#define NHEAD 64
#define PAD 3
#define XSTRIDE (TT*HWPIX)      // per-channel stride in x
#define ROWP 54                 // 48 + 2*3 padded rows
#define COLP 56                 // 48 + 2*3 padded cols (+2 align slack)
#define PLANE (ROWP*COLP*NHEAD) // elements per (b,t) plane

typedef unsigned short bf16_t;

static __device__ __forceinline__ bf16_t f2bf(float f) {
    unsigned u = __float_as_uint(f);
    u += 0x7FFFu + ((u >> 16) & 1u);          // round-to-nearest-even
    return (bf16_t)(u >> 16);
}
static __device__ __forceinline__ float bf_lo(unsigned u) {
    return __uint_as_float(u << 16);
}
static __device__ __forceinline__ float bf_hi(unsigned u) {
    return __uint_as_float(u & 0xFFFF0000u);
}

// v_dot2_f32_bf16 path (hedged: falls back to unpack+fma if unavailable)
#if defined(__has_builtin)
#if __has_builtin(__builtin_amdgcn_fdot2_f32_bf16) && __has_builtin(__builtin_amdgcn_perm)
#define HAVE_DOT2 1
#endif
#endif

#ifdef HAVE_DOT2
typedef __bf16 bf16x2_t __attribute__((ext_vector_type(2)));
static __device__ __forceinline__ float dot2bf(unsigned g2, unsigned a2, float c) {
    return __builtin_amdgcn_fdot2_f32_bf16(
        __builtin_bit_cast(bf16x2_t, g2), __builtin_bit_cast(bf16x2_t, a2), c, false);
}
static __device__ __forceinline__ unsigned perm_lo(unsigned a, unsigned b) {
    return __builtin_amdgcn_perm(a, b, 0x05040100u);
}
static __device__ __forceinline__ unsigned perm_hi(unsigned a, unsigned b) {
    return __builtin_amdgcn_perm(a, b, 0x07060302u);
}
#else
static __device__ __forceinline__ float dot2bf(unsigned g2, unsigned a2, float c) {
    return c + bf_lo(g2) * bf_lo(a2) + bf_hi(g2) * bf_hi(a2);
}
#endif

// ---------------------------------------------------------------------------
// K1: projections. wtrans folded in: each block stages fp32 weights and packs
// to bf16 pairs on the fly (identical layout to the old wt_pk/wp_pk/wg_pk).
// 32 px per block (was 16): halves weight-staging traffic, 128B-coalesced x
// staging. Fully LDS-resident inner loop, bf16 dot2 math.
// ---------------------------------------------------------------------------
__global__ __launch_bounds__(256) void proj_kernel(
    const float* __restrict__ x,
    const float* __restrict__ w_theta,
    const float* __restrict__ w_phi,
    const float* __restrict__ w_g,
    bf16_t* __restrict__ q_b,
    bf16_t* __restrict__ phi_b,
    bf16_t* __restrict__ g_b)
{
    __shared__ unsigned xs[32 * 68];    // 8.5 KB (bf16 c-pairs, pitch 68)
    __shared__ uint4 wlA[1024];         // 16 KB  [ck 0..15][h 0..63]
    __shared__ uint4 wlB[1024];         // 16 KB

    const int bt   = blockIdx.y;        // 0..9
    const int b    = bt / TT;
    const int t    = bt % TT;
    const int tid  = threadIdx.x;
    const int lane = tid & 63;
    const int wv   = tid >> 6;
    const int p0   = blockIdx.x * 32;

    // ---- stage weights from fp32, packing to bf16 pairs ----
    {
        const float* srcA = (t == 0) ? w_theta : w_phi;
#pragma unroll
        for (int i = 0; i < 4; ++i) {
            const int idx = i * 256 + tid;   // 0..1023
            const int h   = idx >> 4;        // 0..63
            const int ck  = idx & 15;        // chunk 0..15
            const float* s = srcA + h * CCH + ck * 8;
            const float4 v0 = *(const float4*)(s);
            const float4 v1 = *(const float4*)(s + 4);
            uint4 o;
            o.x = (unsigned)f2bf(v0.x) | ((unsigned)f2bf(v0.y) << 16);
            o.y = (unsigned)f2bf(v0.z) | ((unsigned)f2bf(v0.w) << 16);
            o.z = (unsigned)f2bf(v1.x) | ((unsigned)f2bf(v1.y) << 16);
            o.w = (unsigned)f2bf(v1.z) | ((unsigned)f2bf(v1.w) << 16);
            wlA[(ck << 6) | h] = o;
        }
        if (t != 0) {
#pragma unroll
            for (int i = 0; i < 4; ++i) {
                const int idx = i * 256 + tid;
                const int h   = idx >> 4;
                const int ck  = idx & 15;
                const float* s = w_g + h * CCH + ck * 8;
                const float4 v0 = *(const float4*)(s);
                const float4 v1 = *(const float4*)(s + 4);
                uint4 o;
                o.x = (unsigned)f2bf(v0.x) | ((unsigned)f2bf(v0.y) << 16);
                o.y = (unsigned)f2bf(v0.z) | ((unsigned)f2bf(v0.w) << 16);
                o.z = (unsigned)f2bf(v1.x) | ((unsigned)f2bf(v1.y) << 16);
                o.w = (unsigned)f2bf(v1.z) | ((unsigned)f2bf(v1.w) << 16);
                wlB[(ck << 6) | h] = o;
            }
        }
    }

    // ---- stage x tile as bf16 pairs (lanes over 32 px: 128B coalesced) ----
    {
        const float* xsrc = x + ((size_t)(b * CCH) * TT + t) * HWPIX + p0;
#pragma unroll
        for (int i = 0; i < 8; ++i) {
            const int idx = i * 256 + tid;  // 0..2047
            const int cp  = idx >> 5;       // c-pair 0..63
            const int px  = idx & 31;
            const float a0 = xsrc[(size_t)(2 * cp)     * XSTRIDE + px];
            const float a1 = xsrc[(size_t)(2 * cp + 1) * XSTRIDE + px];
            xs[px * 68 + cp] = (unsigned)f2bf(a0) | ((unsigned)f2bf(a1) << 16);
        }
    }
    __syncthreads();

    const int pxb = wv * 8;

    if (t == 0) {
        float acc[8];
#pragma unroll
        for (int p = 0; p < 8; ++p) acc[p] = 0.f;
#pragma unroll 4
        for (int ck = 0; ck < 16; ++ck) {
            const uint4 wa = wlA[(ck << 6) | lane];
#pragma unroll
            for (int p = 0; p < 8; ++p) {
                const uint4 xv = *(const uint4*)&xs[(pxb + p) * 68 + (ck << 2)];
                acc[p] = dot2bf(wa.x, xv.x, acc[p]);
                acc[p] = dot2bf(wa.y, xv.y, acc[p]);
                acc[p] = dot2bf(wa.z, xv.z, acc[p]);
                acc[p] = dot2bf(wa.w, xv.w, acc[p]);
            }
        }
#pragma unroll
        for (int p = 0; p < 8; ++p)
            q_b[((size_t)b * HWPIX + p0 + pxb + p) * NHEAD + lane] = f2bf(acc[p]);
    } else {
        float accp[8], accg[8];
#pragma unroll
        for (int p = 0; p < 8; ++p) { accp[p] = 0.f; accg[p] = 0.f; }
#pragma unroll 4
        for (int ck = 0; ck < 16; ++ck) {
            const uint4 wa = wlA[(ck << 6) | lane];
            const uint4 wb = wlB[(ck << 6) | lane];
#pragma unroll
            for (int p = 0; p < 8; ++p) {
                const uint4 xv = *(const uint4*)&xs[(pxb + p) * 68 + (ck << 2)];
                accp[p] = dot2bf(wa.x, xv.x, accp[p]);
                accp[p] = dot2bf(wa.y, xv.y, accp[p]);
                accp[p] = dot2bf(wa.z, xv.z, accp[p]);
                accp[p] = dot2bf(wa.w, xv.w, accp[p]);
                accg[p] = dot2bf(wb.x, xv.x, accg[p]);
                accg[p] = dot2bf(wb.y, xv.y, accg[p]);
                accg[p] = dot2bf(wb.z, xv.z, accg[p]);
                accg[p] = dot2bf(wb.w, xv.w, accg[p]);
            }
        }
        const size_t base = (size_t)(b * TC + (t - 1)) * PLANE;
#pragma unroll
        for (int p = 0; p < 8; ++p) {
            const int pix = p0 + pxb + p;
            const int X = pix / WW;
            const int Y = pix % WW;
            const int rs = (X == 0) ? 0 : (X + PAD);
            const int rn = (X == 0 || X == HH - 1) ? (PAD + 1) : 1;
            const int cs = (Y == 0) ? 0 : (Y + PAD);
            const int cn = (Y == 0 || Y == WW - 1) ? (PAD + 1) : 1;
            const bf16_t vp = f2bf(accp[p]);
            const bf16_t vg = f2bf(accg[p]);
            for (int r = 0; r < rn; ++r)
                for (int c = 0; c < cn; ++c) {
                    const size_t pos = base + ((size_t)(rs + r) * COLP + (cs + c)) * NHEAD + lane;
                    phi_b[pos] = vp;
                    g_b[pos]   = vg;
                }
        }
    }
}

// ---------------------------------------------------------------------------
// K2: per-t attention partial (R12 optimum — UNCHANGED this round).
// Raw bf16 windows in LDS, bf16 q, dot2 both phases. Single window buffer,
// serialized staging — inter-block overlap at ~6 blocks/CU hides the fetches
// (R13/R14 falsified intra-block alternatives).
// ---------------------------------------------------------------------------
__global__ __launch_bounds__(256) void attn_kernel(
    const bf16_t* __restrict__ q_b,
    const bf16_t* __restrict__ phi_b,
    const bf16_t* __restrict__ g_b,
    float* __restrict__ part_ml,
    bf16_t* __restrict__ part_y)
{
    __shared__ bf16_t win[154 * NHEAD];     // 19.7 KB raw bf16, swizzled
    __shared__ float ls[16][52];            // 49 exp-weights per px
    __shared__ unsigned ls2[16][26];        // packed (a_2m, a_2m+1) bf16 pairs
    __shared__ unsigned prow[26];           // (row0 | row1<<16) per pair

    const int tid = threadIdx.x;
    const int px  = tid >> 4;
    const int sub = tid & 15;
    const int bi  = blockIdx.x;
    const int btc = bi & 7;                 // b*4 + t
    const int b   = btc >> 2;
    const int t   = btc & 3;
    const int rest = bi >> 3;               // 0..143
    const int Y0  = (rest % 3) * 16;
    const int X   = rest / 3;               // 0..47
    const int gpix = X * WW + Y0 + px;

    uint4 qu[8];
    {
        const uint4* qs = (const uint4*)(q_b + ((size_t)b * HWPIX + gpix) * NHEAD);
#pragma unroll
        for (int ch = 0; ch < 8; ++ch) qu[ch] = qs[ch];
    }

    if (tid < 25) {
        const int k0 = 2 * tid;
        const int k1 = (k0 + 1 < 49) ? k0 + 1 : 48;
        const unsigned r0 = (k0 / 7) * 22 + (k0 % 7);
        const unsigned r1 = (k1 / 7) * 22 + (k1 % 7);
        prow[tid] = r0 | (r1 << 16);
    }

    // ---- stage phi window (raw bf16, slot swizzle (ch+row)&7) ----
    {
        const bf16_t* src = phi_b + (size_t)(b * TC + t) * PLANE;
        for (int idx = tid; idx < 1232; idx += 256) {
            const int row = idx >> 3;
            const int ch  = idx & 7;
            const int i   = row / 22;
            const int c   = row - i * 22;
            const uint4 u = *(const uint4*)(src + ((size_t)((X + i) * COLP) + Y0 + c) * NHEAD + ch * 8);
            *(uint4*)&win[row * 64 + (((ch + row) & 7) << 3)] = u;
        }
    }
    __syncthreads();

    // ---- 49-key logits ----
    float v[4];
#pragma unroll
    for (int r = 0; r < 4; ++r) {
        const int k = sub + 16 * r;
        float d = -INFINITY;
        if (k < 49) {
            const int i = k / 7;
            const int j = k - i * 7;
            const int row = i * 22 + j + px;
            const bf16_t* base = &win[row * 64];
            float s = 0.f;
#pragma unroll
            for (int ch = 0; ch < 8; ++ch) {
                const uint4 u = *(const uint4*)&base[((ch + row) & 7) << 3];
                s = dot2bf(u.x, qu[ch].x, s);
                s = dot2bf(u.y, qu[ch].y, s);
                s = dot2bf(u.z, qu[ch].z, s);
                s = dot2bf(u.w, qu[ch].w, s);
            }
            d = s * 8.0f;    // * sqrt(64)
        }
        v[r] = d;
    }
    float m = fmaxf(fmaxf(v[0], v[1]), fmaxf(v[2], v[3]));
#pragma unroll
    for (int d = 1; d < 16; d <<= 1) m = fmaxf(m, __shfl_xor(m, d));
    float lsum = 0.f;
#pragma unroll
    for (int r = 0; r < 4; ++r) {
        const int k = sub + 16 * r;
        if (k < 49) {
            const float e = __expf(v[r] - m);
            ls[px][k] = e;
            lsum += e;
        }
    }
#pragma unroll
    for (int d = 1; d < 16; d <<= 1) lsum += __shfl_xor(lsum, d);
    if (sub == 0) {
        *(float2*)&part_ml[((size_t)(b * TC + t) * HWPIX + gpix) * 2] = make_float2(m, lsum);
    }

#pragma unroll
    for (int mq = 0; mq < 2; ++mq) {
        const int mm = sub + 16 * mq;
        if (mm < 25) {
            const float a0 = ls[px][2 * mm];
            const float a1 = (2 * mm + 1 < 49) ? ls[px][2 * mm + 1] : 0.f;
            ls2[px][mm] = (unsigned)f2bf(a0) | ((unsigned)f2bf(a1) << 16);
        }
    }
    __syncthreads();

    // ---- stage g window ----
    {
        const bf16_t* src = g_b + (size_t)(b * TC + t) * PLANE;
        for (int idx = tid; idx < 1232; idx += 256) {
            const int row = idx >> 3;
            const int ch  = idx & 7;
            const int i   = row / 22;
            const int c   = row - i * 22;
            const uint4 u = *(const uint4*)(src + ((size_t)((X + i) * COLP) + Y0 + c) * NHEAD + ch * 8);
            *(uint4*)&win[row * 64 + (((ch + row) & 7) << 3)] = u;
        }
    }
    __syncthreads();

    // ---- unnormalized y partial: thread = (px, oct, par) over key-pairs ----
    {
        const int oct = sub >> 1;
        const int par = sub & 1;
        float acc[8];
#pragma unroll
        for (int e = 0; e < 8; ++e) acc[e] = 0.f;
#ifdef HAVE_DOT2
#pragma unroll
        for (int mm = 0; mm < 13; ++mm) {
            const int pm = 2 * mm + par;
            if (pm < 25) {
                const unsigned pr = prow[pm];
                const int row0 = (int)(pr & 0xFFFFu) + px;
                const int row1 = (int)(pr >> 16) + px;
                const unsigned a2 = ls2[px][pm];
                const uint4 u0 = *(const uint4*)&win[row0 * 64 + (((oct + row0) & 7) << 3)];
                const uint4 u1 = *(const uint4*)&win[row1 * 64 + (((oct + row1) & 7) << 3)];
                acc[0] = dot2bf(perm_lo(u1.x, u0.x), a2, acc[0]);
                acc[1] = dot2bf(perm_hi(u1.x, u0.x), a2, acc[1]);
                acc[2] = dot2bf(perm_lo(u1.y, u0.y), a2, acc[2]);
                acc[3] = dot2bf(perm_hi(u1.y, u0.y), a2, acc[3]);
                acc[4] = dot2bf(perm_lo(u1.z, u0.z), a2, acc[4]);
                acc[5] = dot2bf(perm_hi(u1.z, u0.z), a2, acc[5]);
                acc[6] = dot2bf(perm_lo(u1.w, u0.w), a2, acc[6]);
                acc[7] = dot2bf(perm_hi(u1.w, u0.w), a2, acc[7]);
            }
        }
#else
#pragma unroll
        for (int mm = 0; mm < 25; ++mm) {
            const int kk = 2 * mm + par;
            if (kk < 49) {
                const int i = kk / 7;
                const int j = kk - i * 7;
                const int row = i * 22 + j + px;
                const float a = ls[px][kk];
                const uint4 u = *(const uint4*)&win[row * 64 + (((oct + row) & 7) << 3)];
                acc[0] = fmaf(a, bf_lo(u.x), acc[0]);
                acc[1] = fmaf(a, bf_hi(u.x), acc[1]);
                acc[2] = fmaf(a, bf_lo(u.y), acc[2]);
                acc[3] = fmaf(a, bf_hi(u.y), acc[3]);
                acc[4] = fmaf(a, bf_lo(u.z), acc[4]);
                acc[5] = fmaf(a, bf_hi(u.z), acc[5]);
                acc[6] = fmaf(a, bf_lo(u.w), acc[6]);
                acc[7] = fmaf(a, bf_hi(u.w), acc[7]);
            }
        }
#endif
#pragma unroll
        for (int e = 0; e < 8; ++e) acc[e] += __shfl_xor(acc[e], 1);
        if (par == 0) {
            uint4 o;
            o.x = (unsigned)f2bf(acc[0]) | ((unsigned)f2bf(acc[1]) << 16);
            o.y = (unsigned)f2bf(acc[2]) | ((unsigned)f2bf(acc[3]) << 16);
            o.z = (unsigned)f2bf(acc[4]) | ((unsigned)f2bf(acc[5]) << 16);
            o.w = (unsigned)f2bf(acc[6]) | ((unsigned)f2bf(acc[7]) << 16);
            *(uint4*)(part_y + ((size_t)(b * TC + t) * HWPIX + gpix) * NHEAD + (oct << 3)) = o;
        }
    }
}

// ---------------------------------------------------------------------------
// K3: combine 4 t-partials + out-proj + residual. Grid (3,48,8): z = b*4+cg.
// w_out tile staged in LDS (wtrans killed); phase-2 remapped so lanes vary px
// for fixed channel: x residual read and out store are 64B-contiguous.
// ---------------------------------------------------------------------------
__global__ __launch_bounds__(256) void combine_kernel(
    const float* __restrict__ x,
    const float* __restrict__ w_out,
    const float* __restrict__ part_ml,
    const bf16_t* __restrict__ part_y,
    float* __restrict__ out)
{
    __shared__ float y_s[16][68];
    __shared__ float wo_s[32][68];   // [c-local][h], pitch 68 (16B-aligned rows)

    const int tid = threadIdx.x;
    const int px  = tid >> 4;
    const int sub = tid & 15;
    const int Y0  = blockIdx.x * 16;
    const int X   = blockIdx.y;
    const int bz  = blockIdx.z;
    const int b   = bz >> 2;
    const int cg  = bz & 3;
    const int gpix = X * WW + Y0 + px;

    // ---- stage w_out tile: rows c = cg*32..+31, all 64 h (8.7 KB) ----
    {
#pragma unroll
        for (int i = 0; i < 2; ++i) {
            const int idx = i * 256 + tid;   // 0..511
            const int c   = idx >> 4;        // 0..31
            const int hq  = idx & 15;        // 0..15
            const float4 v = *(const float4*)(w_out + (size_t)(cg * 32 + c) * NHEAD + hq * 4);
            *(float4*)&wo_s[c][hq * 4] = v;
        }
    }

    const float* mlb = part_ml + ((size_t)b * TC * HWPIX + gpix) * 2;
    float mt[TC], lt[TC];
#pragma unroll
    for (int t = 0; t < TC; ++t) {
        const float2 ml = *(const float2*)(mlb + (size_t)t * HWPIX * 2);
        mt[t] = ml.x; lt[t] = ml.y;
    }
    const float M = fmaxf(fmaxf(mt[0], mt[1]), fmaxf(mt[2], mt[3]));
    float st[TC], L = 0.f;
#pragma unroll
    for (int t = 0; t < TC; ++t) { st[t] = __expf(mt[t] - M); L += lt[t] * st[t]; }
    const float inv = 1.0f / L;
#pragma unroll
    for (int t = 0; t < TC; ++t) st[t] *= inv;

    float4 acc = make_float4(0.f, 0.f, 0.f, 0.f);
    const bf16_t* pyb = part_y + ((size_t)b * TC * HWPIX + gpix) * NHEAD + (sub << 2);
#pragma unroll
    for (int t = 0; t < TC; ++t) {
        const ushort4 u = *(const ushort4*)(pyb + (size_t)t * HWPIX * NHEAD);
        const float s = st[t];
        acc.x = fmaf(s, __uint_as_float(((unsigned)u.x) << 16), acc.x);
        acc.y = fmaf(s, __uint_as_float(((unsigned)u.y) << 16), acc.y);
        acc.z = fmaf(s, __uint_as_float(((unsigned)u.z) << 16), acc.z);
        acc.w = fmaf(s, __uint_as_float(((unsigned)u.w) << 16), acc.w);
    }
    *(float4*)&y_s[px][sub * 4] = acc;
    __syncthreads();

    // ---- out-projection + residual: thread = (c-local, px2); lanes vary px2
    //      so x read / out write are 64B-contiguous per channel ----
    {
        const int px2 = tid & 15;           // pixel within strip
        const int cl  = tid >> 4;           // 0..15 (channel-local base)
        const int gpix2 = X * WW + Y0 + px2;
#pragma unroll
        for (int it = 0; it < 2; ++it) {
            const int c = cl + 16 * it;     // 0..31
            float o = 0.f;
#pragma unroll
            for (int h0 = 0; h0 < 16; ++h0) {
                const float4 yv = *(const float4*)&y_s[px2][h0 * 4];
                const float4 wv = *(const float4*)&wo_s[c][h0 * 4];
                o = fmaf(wv.x, yv.x, o);
                o = fmaf(wv.y, yv.y, o);
                o = fmaf(wv.z, yv.z, o);
                o = fmaf(wv.w, yv.w, o);
            }
            const size_t cc = (size_t)(b * CCH + cg * 32 + c);
            const float xi = x[cc * TT * HWPIX + gpix2];
            out[cc * HWPIX + gpix2] = xi + o;
        }
    }
}

// ---------------------------------------------------------------------------
extern "C" void kernel_launch(void* const* d_in, const int* in_sizes, int n_in,
                              void* d_out, int out_size, void* d_ws, size_t ws_size,
                              hipStream_t stream)
{
    const float* x       = (const float*)d_in[0];
    const float* w_theta = (const float*)d_in[1];
    const float* w_phi   = (const float*)d_in[2];
    const float* w_g     = (const float*)d_in[3];
    const float* w_out   = (const float*)d_in[4];
    float* out = (float*)d_out;

    bf16_t* q_b    = (bf16_t*)d_ws;                              // 294912 us
    bf16_t* phi_b  = q_b + (size_t)BATCH * HWPIX * NHEAD;        // 1548288 us
    bf16_t* g_b    = phi_b + (size_t)BATCH * TC * PLANE;         // 1548288 us
    float*  part_ml = (float*)(g_b + (size_t)BATCH * TC * PLANE); // 36864 f
    bf16_t* part_y  = (bf16_t*)(part_ml + 36864);                // 1179648 us

    dim3 g1(HWPIX / 32, BATCH * TT);            // (72, 10)
    proj_kernel<<<g1, 256, 0, stream>>>(x, w_theta, w_phi, w_g, q_b, phi_b, g_b);

    attn_kernel<<<BATCH * TC * HH * (WW / 16), 256, 0, stream>>>(
        q_b, phi_b, g_b, part_ml, part_y);      // 1152 blocks

    dim3 g3(WW / 16, HH, BATCH * 4);            // (3, 48, 8)
    combine_kernel<<<g3, 256, 0, stream>>>(x, w_out, part_ml, part_y, out);
}

// Round 2
// 98.997 us; speedup vs baseline: 1.0965x; 1.0637x over previous
//
#include <hip/hip_runtime.h>
#include <hip/hip_bf16.h>
#include <math.h>

// B=2, C=128, T=5 (Tc=4 ctx), H=W=48, heads=64, PATCH=7 (pad 3), K=196.
#define BATCH 2
#define CCH 128
#define TT 5
#define TC 4
#define HH 48
#define WW 48
#define HWPIX 2304
#define NHEAD 64
#define PAD 3
#define XSTRIDE (TT*HWPIX)      // per-channel stride in x
#define ROWP 54                 // 48 + 2*3 padded rows
#define COLP 56                 // 48 + 2*3 padded cols (+2 align slack)
#define PLANE (ROWP*COLP*NHEAD) // elements per (b,t) plane
#define GOFF (BATCH*TC*PLANE)   // g_b offset from phi_b (elements)

// fused-attn tile geometry: 4 wide x 2 tall pixel tile
#define TW 4
#define TH 2
#define WROWS 8                 // TH + 6
#define WCOLS 10                // TW + 6
#define NRC 80                  // WROWS*WCOLS
#define WELEM (NRC*NHEAD)       // 5120 bf16 per window buffer

typedef unsigned short bf16_t;

static __device__ __forceinline__ bf16_t f2bf(float f) {
    unsigned u = __float_as_uint(f);
    u += 0x7FFFu + ((u >> 16) & 1u);          // round-to-nearest-even
    return (bf16_t)(u >> 16);
}
static __device__ __forceinline__ float bf_lo(unsigned u) {
    return __uint_as_float(u << 16);
}
static __device__ __forceinline__ float bf_hi(unsigned u) {
    return __uint_as_float(u & 0xFFFF0000u);
}

// v_dot2_f32_bf16 path (hedged: falls back to unpack+fma if unavailable)
#if defined(__has_builtin)
#if __has_builtin(__builtin_amdgcn_fdot2_f32_bf16) && __has_builtin(__builtin_amdgcn_perm)
#define HAVE_DOT2 1
#endif
#endif

#ifdef HAVE_DOT2
typedef __bf16 bf16x2_t __attribute__((ext_vector_type(2)));
static __device__ __forceinline__ float dot2bf(unsigned g2, unsigned a2, float c) {
    return __builtin_amdgcn_fdot2_f32_bf16(
        __builtin_bit_cast(bf16x2_t, g2), __builtin_bit_cast(bf16x2_t, a2), c, false);
}
static __device__ __forceinline__ unsigned perm_lo(unsigned a, unsigned b) {
    return __builtin_amdgcn_perm(a, b, 0x05040100u);
}
static __device__ __forceinline__ unsigned perm_hi(unsigned a, unsigned b) {
    return __builtin_amdgcn_perm(a, b, 0x07060302u);
}
#else
static __device__ __forceinline__ float dot2bf(unsigned g2, unsigned a2, float c) {
    return c + bf_lo(g2) * bf_lo(a2) + bf_hi(g2) * bf_hi(a2);
}
#endif

// ---------------------------------------------------------------------------
// K1: projections (unchanged from R1). 32 px per block, weights packed on the
// fly to bf16 pairs in LDS, fully LDS-resident dot2 inner loop. Writes q and
// replicate-padded phi/g planes.
// ---------------------------------------------------------------------------
__global__ __launch_bounds__(256) void proj_kernel(
    const float* __restrict__ x,
    const float* __restrict__ w_theta,
    const float* __restrict__ w_phi,
    const float* __restrict__ w_g,
    bf16_t* __restrict__ q_b,
    bf16_t* __restrict__ phi_b,
    bf16_t* __restrict__ g_b)
{
    __shared__ unsigned xs[32 * 68];    // 8.5 KB (bf16 c-pairs, pitch 68)
    __shared__ uint4 wlA[1024];         // 16 KB  [ck 0..15][h 0..63]
    __shared__ uint4 wlB[1024];         // 16 KB

    const int bt   = blockIdx.y;        // 0..9
    const int b    = bt / TT;
    const int t    = bt % TT;
    const int tid  = threadIdx.x;
    const int lane = tid & 63;
    const int wv   = tid >> 6;
    const int p0   = blockIdx.x * 32;

    // ---- stage weights from fp32, packing to bf16 pairs ----
    {
        const float* srcA = (t == 0) ? w_theta : w_phi;
#pragma unroll
        for (int i = 0; i < 4; ++i) {
            const int idx = i * 256 + tid;   // 0..1023
            const int h   = idx >> 4;        // 0..63
            const int ck  = idx & 15;        // chunk 0..15
            const float* s = srcA + h * CCH + ck * 8;
            const float4 v0 = *(const float4*)(s);
            const float4 v1 = *(const float4*)(s + 4);
            uint4 o;
            o.x = (unsigned)f2bf(v0.x) | ((unsigned)f2bf(v0.y) << 16);
            o.y = (unsigned)f2bf(v0.z) | ((unsigned)f2bf(v0.w) << 16);
            o.z = (unsigned)f2bf(v1.x) | ((unsigned)f2bf(v1.y) << 16);
            o.w = (unsigned)f2bf(v1.z) | ((unsigned)f2bf(v1.w) << 16);
            wlA[(ck << 6) | h] = o;
        }
        if (t != 0) {
#pragma unroll
            for (int i = 0; i < 4; ++i) {
                const int idx = i * 256 + tid;
                const int h   = idx >> 4;
                const int ck  = idx & 15;
                const float* s = w_g + h * CCH + ck * 8;
                const float4 v0 = *(const float4*)(s);
                const float4 v1 = *(const float4*)(s + 4);
                uint4 o;
                o.x = (unsigned)f2bf(v0.x) | ((unsigned)f2bf(v0.y) << 16);
                o.y = (unsigned)f2bf(v0.z) | ((unsigned)f2bf(v0.w) << 16);
                o.z = (unsigned)f2bf(v1.x) | ((unsigned)f2bf(v1.y) << 16);
                o.w = (unsigned)f2bf(v1.z) | ((unsigned)f2bf(v1.w) << 16);
                wlB[(ck << 6) | h] = o;
            }
        }
    }

    // ---- stage x tile as bf16 pairs (lanes over 32 px: 128B coalesced) ----
    {
        const float* xsrc = x + ((size_t)(b * CCH) * TT + t) * HWPIX + p0;
#pragma unroll
        for (int i = 0; i < 8; ++i) {
            const int idx = i * 256 + tid;  // 0..2047
            const int cp  = idx >> 5;       // c-pair 0..63
            const int px  = idx & 31;
            const float a0 = xsrc[(size_t)(2 * cp)     * XSTRIDE + px];
            const float a1 = xsrc[(size_t)(2 * cp + 1) * XSTRIDE + px];
            xs[px * 68 + cp] = (unsigned)f2bf(a0) | ((unsigned)f2bf(a1) << 16);
        }
    }
    __syncthreads();

    const int pxb = wv * 8;

    if (t == 0) {
        float acc[8];
#pragma unroll
        for (int p = 0; p < 8; ++p) acc[p] = 0.f;
#pragma unroll 4
        for (int ck = 0; ck < 16; ++ck) {
            const uint4 wa = wlA[(ck << 6) | lane];
#pragma unroll
            for (int p = 0; p < 8; ++p) {
                const uint4 xv = *(const uint4*)&xs[(pxb + p) * 68 + (ck << 2)];
                acc[p] = dot2bf(wa.x, xv.x, acc[p]);
                acc[p] = dot2bf(wa.y, xv.y, acc[p]);
                acc[p] = dot2bf(wa.z, xv.z, acc[p]);
                acc[p] = dot2bf(wa.w, xv.w, acc[p]);
            }
        }
#pragma unroll
        for (int p = 0; p < 8; ++p)
            q_b[((size_t)b * HWPIX + p0 + pxb + p) * NHEAD + lane] = f2bf(acc[p]);
    } else {
        float accp[8], accg[8];
#pragma unroll
        for (int p = 0; p < 8; ++p) { accp[p] = 0.f; accg[p] = 0.f; }
#pragma unroll 4
        for (int ck = 0; ck < 16; ++ck) {
            const uint4 wa = wlA[(ck << 6) | lane];
            const uint4 wb = wlB[(ck << 6) | lane];
#pragma unroll
            for (int p = 0; p < 8; ++p) {
                const uint4 xv = *(const uint4*)&xs[(pxb + p) * 68 + (ck << 2)];
                accp[p] = dot2bf(wa.x, xv.x, accp[p]);
                accp[p] = dot2bf(wa.y, xv.y, accp[p]);
                accp[p] = dot2bf(wa.z, xv.z, accp[p]);
                accp[p] = dot2bf(wa.w, xv.w, accp[p]);
                accg[p] = dot2bf(wb.x, xv.x, accg[p]);
                accg[p] = dot2bf(wb.y, xv.y, accg[p]);
                accg[p] = dot2bf(wb.z, xv.z, accg[p]);
                accg[p] = dot2bf(wb.w, xv.w, accg[p]);
            }
        }
        const size_t base = (size_t)(b * TC + (t - 1)) * PLANE;
#pragma unroll
        for (int p = 0; p < 8; ++p) {
            const int pix = p0 + pxb + p;
            const int X = pix / WW;
            const int Y = pix % WW;
            const int rs = (X == 0) ? 0 : (X + PAD);
            const int rn = (X == 0 || X == HH - 1) ? (PAD + 1) : 1;
            const int cs = (Y == 0) ? 0 : (Y + PAD);
            const int cn = (Y == 0 || Y == WW - 1) ? (PAD + 1) : 1;
            const bf16_t vp = f2bf(accp[p]);
            const bf16_t vg = f2bf(accg[p]);
            for (int r = 0; r < rn; ++r)
                for (int c = 0; c < cn; ++c) {
                    const size_t pos = base + ((size_t)(rs + r) * COLP + (cs + c)) * NHEAD + lane;
                    phi_b[pos] = vp;
                    g_b[pos]   = vg;
                }
        }
    }
}

// ---------------------------------------------------------------------------
// K2: FUSED attention + combine + out-projection + residual.
// One block = 4x2 pixel tile x all 4 t's, online softmax across t (fp32
// rescale — better numerics than the old bf16 part_y round-trip).
// Double-buffered phi/g windows (8x10 rowcols = 12.5 KB each) with
// issue-early/write-late staging; one barrier per t. Epilogue aliases the
// window LDS for the w_out tile and does out-proj + residual in-block.
// 576 blocks, 43.5 KB LDS -> 3 blocks/CU, whole grid co-resident.
// ---------------------------------------------------------------------------
__global__ __launch_bounds__(256) void attn_fused_kernel(
    const float* __restrict__ x,
    const bf16_t* __restrict__ q_b,
    const bf16_t* __restrict__ pg,      // phi planes; g planes at pg + GOFF
    const float* __restrict__ w_out,
    float* __restrict__ out)
{
    __shared__ __align__(16) char smem[4 * WELEM * 2];  // 40960 B win / alias
    __shared__ float ls[8][52];
    __shared__ unsigned ls2[8][26];
    __shared__ unsigned prow[26];

    const int tid = threadIdx.x;
    const int px  = tid >> 5;           // 0..7 pixel of tile
    const int sub = tid & 31;
    const int Y0  = blockIdx.x * TW;
    const int X0  = blockIdx.y * TH;
    const int b   = blockIdx.z;
    const int rr  = px >> 2;
    const int cc  = px & 3;
    const int gpix  = (X0 + rr) * WW + Y0 + cc;
    const int pxoff = rr * WCOLS + cc;
    const int oct = sub >> 2;
    const int par = sub & 3;

    // ---- q fragments (64 h = 8 uint4), broadcast across 32 sub-lanes ----
    uint4 qu[8];
    {
        const uint4* qs = (const uint4*)(q_b + ((size_t)b * HWPIX + gpix) * NHEAD);
#pragma unroll
        for (int ch = 0; ch < 8; ++ch) qu[ch] = qs[ch];
    }

    if (tid < 25) {
        const int k0 = 2 * tid;
        const int k1 = (k0 + 1 < 49) ? k0 + 1 : 48;
        const unsigned r0 = (unsigned)((k0 / 7) * WCOLS + (k0 % 7));
        const unsigned r1 = (unsigned)((k1 / 7) * WCOLS + (k1 % 7));
        prow[tid] = r0 | (r1 << 16);
    }

    // ---- per-thread staging offsets: 1280 uint4 per stage = 5/thread ----
    int srcoff[5], lddst[5];
#pragma unroll
    for (int ii = 0; ii < 5; ++ii) {
        const int idx  = ii * 256 + tid;          // 0..1279
        const int isg  = (idx >= 640) ? 1 : 0;    // 0: phi, 1: g
        const int idx2 = idx - (isg ? 640 : 0);
        const int row  = idx2 >> 3;               // 0..79
        const int ch   = idx2 & 7;
        const int i    = row / WCOLS;
        const int c    = row - i * WCOLS;
        srcoff[ii] = isg * GOFF + ((X0 + i) * COLP + Y0 + c) * NHEAD + ch * 8;
        lddst[ii]  = isg * (2 * WELEM) + row * NHEAD + (((ch + row) & 7) << 3);
    }

    bf16_t* winb = (bf16_t*)smem;   // [phi0 | phi1 | g0 | g1], 5120 elems each

    // ---- prologue: stage t=0 into parity 0 ----
    {
        const bf16_t* sp = pg + (size_t)(b * TC) * PLANE;
#pragma unroll
        for (int ii = 0; ii < 5; ++ii) {
            const uint4 v = *(const uint4*)(sp + srcoff[ii]);
            *(uint4*)(winb + lddst[ii]) = v;
        }
    }
    __syncthreads();

    float m_run = -INFINITY, l_run = 0.f;
    float acc[8];
#pragma unroll
    for (int e = 0; e < 8; ++e) acc[e] = 0.f;

    for (int t = 0; t < TC; ++t) {
        const int p = t & 1;

        // ---- issue next-t loads early (hidden under logits+PV) ----
        uint4 stg[5];
        if (t < TC - 1) {
            const bf16_t* sp = pg + (size_t)(b * TC + t + 1) * PLANE;
#pragma unroll
            for (int ii = 0; ii < 5; ++ii)
                stg[ii] = *(const uint4*)(sp + srcoff[ii]);
        }

        // ---- logits: keys k = sub and sub+32 ----
        const bf16_t* pbase = winb + p * WELEM;
        float v0, v1 = -INFINITY;
        {
            const int k = sub;
            const int i = k / 7, j = k - i * 7;
            const int row = i * WCOLS + j + pxoff;
            const bf16_t* base = pbase + row * NHEAD;
            float s = 0.f;
#pragma unroll
            for (int ch = 0; ch < 8; ++ch) {
                const uint4 u = *(const uint4*)&base[((ch + row) & 7) << 3];
                s = dot2bf(u.x, qu[ch].x, s);
                s = dot2bf(u.y, qu[ch].y, s);
                s = dot2bf(u.z, qu[ch].z, s);
                s = dot2bf(u.w, qu[ch].w, s);
            }
            v0 = s * 8.0f;    // * sqrt(64)
        }
        if (sub + 32 < 49) {
            const int k = sub + 32;
            const int i = k / 7, j = k - i * 7;
            const int row = i * WCOLS + j + pxoff;
            const bf16_t* base = pbase + row * NHEAD;
            float s = 0.f;
#pragma unroll
            for (int ch = 0; ch < 8; ++ch) {
                const uint4 u = *(const uint4*)&base[((ch + row) & 7) << 3];
                s = dot2bf(u.x, qu[ch].x, s);
                s = dot2bf(u.y, qu[ch].y, s);
                s = dot2bf(u.z, qu[ch].z, s);
                s = dot2bf(u.w, qu[ch].w, s);
            }
            v1 = s * 8.0f;
        }

        // ---- online softmax update (per px-group of 32 lanes) ----
        float mt = fmaxf(v0, v1);
#pragma unroll
        for (int d = 1; d < 32; d <<= 1) mt = fmaxf(mt, __shfl_xor(mt, d));
        const float m_new = fmaxf(m_run, mt);
        const float sc = __expf(m_run - m_new);
        const float e0 = __expf(v0 - m_new);
        float lsum = e0;
        ls[px][sub] = e0;
        if (sub + 32 < 49) {
            const float e1 = __expf(v1 - m_new);
            ls[px][sub + 32] = e1;
            lsum += e1;
        }
#pragma unroll
        for (int d = 1; d < 32; d <<= 1) lsum += __shfl_xor(lsum, d);
        m_run = m_new;
        l_run = l_run * sc + lsum;

        if (sub < 25) {
            const float a0 = ls[px][2 * sub];
            const float a1 = (2 * sub + 1 < 49) ? ls[px][2 * sub + 1] : 0.f;
            ls2[px][sub] = (unsigned)f2bf(a0) | ((unsigned)f2bf(a1) << 16);
        }

        // ---- PV accumulate with rescale ----
#pragma unroll
        for (int e = 0; e < 8; ++e) acc[e] *= sc;
        const bf16_t* gbase = winb + 2 * WELEM + p * WELEM;
#pragma unroll
        for (int mi = 0; mi < 7; ++mi) {
            const int pm = par + 4 * mi;
            if (pm < 25) {
                const unsigned pr = prow[pm];
                const int row0 = (int)(pr & 0xFFFFu) + pxoff;
                const int row1 = (int)(pr >> 16) + pxoff;
                const uint4 u0 = *(const uint4*)&gbase[row0 * NHEAD + (((oct + row0) & 7) << 3)];
                const uint4 u1 = *(const uint4*)&gbase[row1 * NHEAD + (((oct + row1) & 7) << 3)];
#ifdef HAVE_DOT2
                const unsigned a2 = ls2[px][pm];
                acc[0] = dot2bf(perm_lo(u1.x, u0.x), a2, acc[0]);
                acc[1] = dot2bf(perm_hi(u1.x, u0.x), a2, acc[1]);
                acc[2] = dot2bf(perm_lo(u1.y, u0.y), a2, acc[2]);
                acc[3] = dot2bf(perm_hi(u1.y, u0.y), a2, acc[3]);
                acc[4] = dot2bf(perm_lo(u1.z, u0.z), a2, acc[4]);
                acc[5] = dot2bf(perm_hi(u1.z, u0.z), a2, acc[5]);
                acc[6] = dot2bf(perm_lo(u1.w, u0.w), a2, acc[6]);
                acc[7] = dot2bf(perm_hi(u1.w, u0.w), a2, acc[7]);
#else
                const float a0 = ls[px][2 * pm];
                const float a1 = (2 * pm + 1 < 49) ? ls[px][2 * pm + 1] : 0.f;
                acc[0] = fmaf(a1, bf_lo(u1.x), fmaf(a0, bf_lo(u0.x), acc[0]));
                acc[1] = fmaf(a1, bf_hi(u1.x), fmaf(a0, bf_hi(u0.x), acc[1]));
                acc[2] = fmaf(a1, bf_lo(u1.y), fmaf(a0, bf_lo(u0.y), acc[2]));
                acc[3] = fmaf(a1, bf_hi(u1.y), fmaf(a0, bf_hi(u0.y), acc[3]));
                acc[4] = fmaf(a1, bf_lo(u1.z), fmaf(a0, bf_lo(u0.z), acc[4]));
                acc[5] = fmaf(a1, bf_hi(u1.z), fmaf(a0, bf_hi(u0.z), acc[5]));
                acc[6] = fmaf(a1, bf_lo(u1.w), fmaf(a0, bf_lo(u0.w), acc[6]));
                acc[7] = fmaf(a1, bf_hi(u1.w), fmaf(a0, bf_hi(u0.w), acc[7]));
#endif
            }
        }

        // ---- write-late: next-t windows into alternate buffers ----
        if (t < TC - 1) {
            bf16_t* dp = winb + (p ^ 1) * WELEM;   // g offset baked into lddst
#pragma unroll
            for (int ii = 0; ii < 5; ++ii)
                *(uint4*)(dp + lddst[ii]) = stg[ii];
        }
        __syncthreads();
    }

    // ---- reduce over par (4 key-subsets), normalize ----
#pragma unroll
    for (int e = 0; e < 8; ++e) {
        acc[e] += __shfl_xor(acc[e], 1);
        acc[e] += __shfl_xor(acc[e], 2);
    }
    const float inv = 1.0f / l_run;

    // ---- epilogue: alias win LDS as w_out tile + y tile ----
    float* wo_s = (float*)smem;                        // [128][68] = 34816 B
    float* y_s  = (float*)(smem + 128 * 68 * 4);       // [8][68]   =  2176 B

#pragma unroll
    for (int ii = 0; ii < 8; ++ii) {
        const int idx = ii * 256 + tid;    // 0..2047
        const int c   = idx >> 4;
        const int hq  = idx & 15;
        const float4 v = *(const float4*)(w_out + (size_t)c * NHEAD + hq * 4);
        *(float4*)&wo_s[c * 68 + hq * 4] = v;
    }
    if (par == 0) {
        const float4 o0 = make_float4(acc[0] * inv, acc[1] * inv, acc[2] * inv, acc[3] * inv);
        const float4 o1 = make_float4(acc[4] * inv, acc[5] * inv, acc[6] * inv, acc[7] * inv);
        *(float4*)&y_s[px * 68 + oct * 8]     = o0;
        *(float4*)&y_s[px * 68 + oct * 8 + 4] = o1;
    }
    __syncthreads();

    // ---- out-projection + residual ----
    {
        const int px2 = tid & 7;
        const int cl  = tid >> 3;          // 0..31
        const int rr2 = px2 >> 2, cc2 = px2 & 3;
        const int gpix2 = (X0 + rr2) * WW + Y0 + cc2;
        float o[4] = {0.f, 0.f, 0.f, 0.f};
#pragma unroll
        for (int h0 = 0; h0 < 16; ++h0) {
            const float4 yv = *(const float4*)&y_s[px2 * 68 + h0 * 4];
#pragma unroll
            for (int it = 0; it < 4; ++it) {
                const float4 wv = *(const float4*)&wo_s[(cl + 32 * it) * 68 + h0 * 4];
                o[it] = fmaf(wv.x, yv.x, o[it]);
                o[it] = fmaf(wv.y, yv.y, o[it]);
                o[it] = fmaf(wv.z, yv.z, o[it]);
                o[it] = fmaf(wv.w, yv.w, o[it]);
            }
        }
#pragma unroll
        for (int it = 0; it < 4; ++it) {
            const size_t ccg = (size_t)(b * CCH + cl + 32 * it);
            const float xi = x[ccg * TT * HWPIX + gpix2];
            out[ccg * HWPIX + gpix2] = xi + o[it];
        }
    }
}

// ---------------------------------------------------------------------------
extern "C" void kernel_launch(void* const* d_in, const int* in_sizes, int n_in,
                              void* d_out, int out_size, void* d_ws, size_t ws_size,
                              hipStream_t stream)
{
    const float* x       = (const float*)d_in[0];
    const float* w_theta = (const float*)d_in[1];
    const float* w_phi   = (const float*)d_in[2];
    const float* w_g     = (const float*)d_in[3];
    const float* w_out   = (const float*)d_in[4];
    float* out = (float*)d_out;

    bf16_t* q_b   = (bf16_t*)d_ws;                        // 294912 elems
    bf16_t* phi_b = q_b + (size_t)BATCH * HWPIX * NHEAD;  // 1548288 elems
    bf16_t* g_b   = phi_b + (size_t)GOFF;                 // 1548288 elems

    dim3 g1(HWPIX / 32, BATCH * TT);            // (72, 10)
    proj_kernel<<<g1, 256, 0, stream>>>(x, w_theta, w_phi, w_g, q_b, phi_b, g_b);

    dim3 g2(WW / TW, HH / TH, BATCH);           // (12, 24, 2) = 576 blocks
    attn_fused_kernel<<<g2, 256, 0, stream>>>(x, q_b, phi_b, w_out, out);
}